// Round 1
// baseline (139.185 us; speedup 1.0000x reference)
//
#include <hip/hip_runtime.h>

#define B_ 16
#define N_ 64
#define C_ 128
#define H_ 64
#define W_ 64
#define OUT_CH_ 256
#define MAX_GRID_ 16
#define SCALE_ 0.125f

// ---------------------------------------------------------------------------
// Kernel 1: transpose z [B, C, H*W] -> zf [B, H*W, C] (32x32 LDS tiles)
// so that channel is the contiguous axis for the ROI gather.
// ---------------------------------------------------------------------------
__global__ __launch_bounds__(256) void transpose_kernel(
    const float* __restrict__ z, float* __restrict__ zf) {
  __shared__ float tile[32][33];
  const int HW = H_ * W_;
  int b  = blockIdx.z;   // 0..15
  int ct = blockIdx.y;   // c-tile 0..3   (C/32)
  int pt = blockIdx.x;   // p-tile 0..127 (HW/32)
  int j  = threadIdx.x;  // 0..31
  int i0 = threadIdx.y;  // 0..7

  const float* zb = z + (size_t)b * C_ * HW;
#pragma unroll
  for (int k = 0; k < 4; ++k) {
    int i = i0 + k * 8;
    tile[i][j] = zb[(size_t)(ct * 32 + i) * HW + pt * 32 + j];
  }
  __syncthreads();
  float* zfb = zf + (size_t)b * HW * C_;
#pragma unroll
  for (int k = 0; k < 4; ++k) {
    int i = i0 + k * 8;
    zfb[(size_t)(pt * 32 + i) * C_ + ct * 32 + j] = tile[j][i];
  }
}

// ---------------------------------------------------------------------------
// Kernel 2: fused ROI-align(1x1, adaptive grid, aligned=True) + Linear.
// One block per ROI. 256 threads: c = t&127 (channel), half = t>>7 splits
// grid rows (gy parity). Then LDS reduce + 256-wide Linear epilogue.
// ---------------------------------------------------------------------------
__global__ __launch_bounds__(256) void roi_linear_kernel(
    const float* __restrict__ zf,     // [B, H, W, C]
    const float* __restrict__ boxes,  // [B, N, 4] xyxy
    const float* __restrict__ Wm,     // [OUT_CH, C]
    const float* __restrict__ bias,   // [OUT_CH]
    float* __restrict__ out)          // [B, N, OUT_CH]
{
  int roi  = blockIdx.x;          // b*N + n
  int t    = threadIdx.x;
  int c    = t & 127;
  int half = t >> 7;

  float4 bx = ((const float4*)boxes)[roi];
  float x1 = bx.x * SCALE_ - 0.5f;
  float y1 = bx.y * SCALE_ - 0.5f;
  float x2 = bx.z * SCALE_ - 0.5f;
  float y2 = bx.w * SCALE_ - 0.5f;
  float roi_w = x2 - x1;
  float roi_h = y2 - y1;
  float gwf = fminf(fmaxf(ceilf(roi_w), 1.0f), (float)MAX_GRID_);
  float ghf = fminf(fmaxf(ceilf(roi_h), 1.0f), (float)MAX_GRID_);
  int gw = (int)gwf;
  int gh = (int)ghf;
  float stepx = roi_w / gwf;
  float stepy = roi_h / ghf;

  const float* zb = zf + (size_t)(roi >> 6) * (H_ * W_ * C_);

  float acc = 0.0f;
  for (int gy = half; gy < gh; gy += 2) {
    float sy = y1 + ((float)gy + 0.5f) * stepy;
    bool iry = (sy > -1.0f) && (sy < (float)H_);
    float cy = fmaxf(sy, 0.0f);
    int yl = (int)cy;            // cy >= 0 so trunc == floor
    yl = yl < (H_ - 1) ? yl : (H_ - 1);
    int yh = (yl + 1) < (H_ - 1) ? (yl + 1) : (H_ - 1);
    if (yl >= H_ - 1) cy = (float)yl;
    float fy = cy - (float)yl;
    float hy = 1.0f - fy;

    for (int gx = 0; gx < gw; ++gx) {
      float sx = x1 + ((float)gx + 0.5f) * stepx;
      bool irx = (sx > -1.0f) && (sx < (float)W_);
      if (!(iry && irx)) continue;   // value 0, still counted in gh*gw
      float cx = fmaxf(sx, 0.0f);
      int xl = (int)cx;
      xl = xl < (W_ - 1) ? xl : (W_ - 1);
      int xh = (xl + 1) < (W_ - 1) ? (xl + 1) : (W_ - 1);
      if (xl >= W_ - 1) cx = (float)xl;
      float fx = cx - (float)xl;
      float hx = 1.0f - fx;

      const float* p11 = zb + (size_t)(yl * W_ + xl) * C_;
      const float* p12 = zb + (size_t)(yl * W_ + xh) * C_;
      const float* p21 = zb + (size_t)(yh * W_ + xl) * C_;
      const float* p22 = zb + (size_t)(yh * W_ + xh) * C_;
      acc += hy * hx * p11[c] + hy * fx * p12[c]
           + fy * hx * p21[c] + fy * fx * p22[c];
    }
  }

  __shared__ float part[256];
  __shared__ float feat[128];
  part[t] = acc;
  __syncthreads();
  if (t < 128) {
    feat[t] = (part[t] + part[t + 128]) / (ghf * gwf);
  }
  __syncthreads();

  // Linear: out[roi][t] = bias[t] + sum_c feat[c] * Wm[t][c]
  float sum = bias[t];
  const float* wrow = Wm + (size_t)t * C_;
#pragma unroll 8
  for (int k = 0; k < C_; ++k) {
    sum += feat[k] * wrow[k];
  }
  out[(size_t)roi * OUT_CH_ + t] = sum;
}

extern "C" void kernel_launch(void* const* d_in, const int* in_sizes, int n_in,
                              void* d_out, int out_size, void* d_ws, size_t ws_size,
                              hipStream_t stream) {
  const float* z     = (const float*)d_in[0];  // [B,C,H,W]
  const float* boxes = (const float*)d_in[1];  // [B,N,4]
  const float* Wm    = (const float*)d_in[2];  // [OUT_CH,C]
  const float* bias  = (const float*)d_in[3];  // [OUT_CH]
  float* out = (float*)d_out;
  float* zf  = (float*)d_ws;                   // [B,H,W,C] = 33.5 MB

  dim3 tb(32, 8);
  dim3 tg(H_ * W_ / 32, C_ / 32, B_);
  transpose_kernel<<<tg, tb, 0, stream>>>(z, zf);

  roi_linear_kernel<<<B_ * N_, 256, 0, stream>>>(zf, boxes, Wm, bias, out);
}

// Round 2
// 107.906 us; speedup vs baseline: 1.2899x; 1.2899x over previous
//
#include <hip/hip_runtime.h>

#define B_ 16
#define N_ 64
#define C_ 128
#define H_ 64
#define W_ 64
#define HW_ (H_ * W_)
#define OUT_CH_ 256
#define MAX_GRID_ 16
#define SCALE_ 0.125f

__device__ __forceinline__ unsigned short f2bf(float f) {
  unsigned int u = __float_as_uint(f);
  u = (u + 0x7fffu + ((u >> 16) & 1u)) >> 16;  // round-to-nearest-even
  return (unsigned short)u;
}

// ---------------------------------------------------------------------------
// Kernel 1: z [B, C, HW] fp32 -> zf [B, HW, C] bf16.
// 128(HW) x 128(C) tile per block. Reads: 512B rows; writes: 16B/lane, 1KB/wave.
// LDS row stride 129 shorts keeps bank aliasing <= 2-way.
// ---------------------------------------------------------------------------
__global__ __launch_bounds__(256) void transpose_bf16_kernel(
    const float* __restrict__ z, unsigned short* __restrict__ zf) {
  __shared__ unsigned short tile[128 * 129];
  const int b  = blockIdx.y;
  const int pt = blockIdx.x;  // HW tile, 0..31
  const int t  = threadIdx.x;

  const float* zb = z + (size_t)b * C_ * HW_;
#pragma unroll
  for (int iter = 0; iter < 16; ++iter) {
    int idx = iter * 256 + t;        // 0..4095
    int c   = idx >> 5;              // 0..127
    int p4  = (idx & 31) << 2;       // 0,4,...,124
    float4 v = *(const float4*)(zb + (size_t)c * HW_ + pt * 128 + p4);
    tile[(p4 + 0) * 129 + c] = f2bf(v.x);
    tile[(p4 + 1) * 129 + c] = f2bf(v.y);
    tile[(p4 + 2) * 129 + c] = f2bf(v.z);
    tile[(p4 + 3) * 129 + c] = f2bf(v.w);
  }
  __syncthreads();

  unsigned short* zfb = zf + (size_t)b * HW_ * C_;
#pragma unroll
  for (int iter = 0; iter < 8; ++iter) {
    int idx = iter * 256 + t;        // 0..2047
    int p   = idx >> 4;              // 0..127
    int k8  = (idx & 15) << 3;       // 0,8,...,120
    const unsigned short* src = &tile[p * 129 + k8];
    uint4 u;
    u.x = (unsigned int)src[0] | ((unsigned int)src[1] << 16);
    u.y = (unsigned int)src[2] | ((unsigned int)src[3] << 16);
    u.z = (unsigned int)src[4] | ((unsigned int)src[5] << 16);
    u.w = (unsigned int)src[6] | ((unsigned int)src[7] << 16);
    *(uint4*)(zfb + (size_t)(pt * 128 + p) * C_ + k8) = u;
  }
}

// ---------------------------------------------------------------------------
// Kernel 2: W [OUT_CH, C] -> Wt [C, OUT_CH] (tiny, 32x32 LDS tiles)
// ---------------------------------------------------------------------------
__global__ __launch_bounds__(256) void wtrans_kernel(
    const float* __restrict__ Wm, float* __restrict__ Wt) {
  __shared__ float tile[32][33];
  int ot = blockIdx.x;  // 0..7 over OUT_CH
  int ct = blockIdx.y;  // 0..3 over C
  int j = threadIdx.x, i0 = threadIdx.y;
#pragma unroll
  for (int k = 0; k < 4; ++k) {
    int i = i0 + k * 8;
    tile[i][j] = Wm[(size_t)(ot * 32 + i) * C_ + ct * 32 + j];
  }
  __syncthreads();
#pragma unroll
  for (int k = 0; k < 4; ++k) {
    int i = i0 + k * 8;
    Wt[(size_t)(ct * 32 + i) * OUT_CH_ + ot * 32 + j] = tile[j][i];
  }
}

// ---------------------------------------------------------------------------
// Kernel 3: gather. One wave per (roi, gy) row: block=128 thr, 2 waves,
// wave handles gy = 2*(bid&7) + waveid; lanes = channel pairs (ushort2).
// Writes fp32 row-partials [roi][gy][C] (only for gy < gh).
// ---------------------------------------------------------------------------
__global__ __launch_bounds__(128) void gather_kernel(
    const unsigned short* __restrict__ zf,   // [B, HW, C] bf16
    const float* __restrict__ boxes,         // [B, N, 4]
    float* __restrict__ partial)             // [B*N, 16, C] fp32
{
  int bid = blockIdx.x;       // 0..8191
  int roi = bid >> 3;
  int t   = threadIdx.x;
  int gy  = ((bid & 7) << 1) + (t >> 6);
  int c2  = t & 63;           // channel pair

  float4 bx = ((const float4*)boxes)[roi];
  float x1 = bx.x * SCALE_ - 0.5f;
  float y1 = bx.y * SCALE_ - 0.5f;
  float roi_w = bx.z * SCALE_ - 0.5f - x1;
  float roi_h = bx.w * SCALE_ - 0.5f - y1;
  float gwf = fminf(fmaxf(ceilf(roi_w), 1.0f), (float)MAX_GRID_);
  float ghf = fminf(fmaxf(ceilf(roi_h), 1.0f), (float)MAX_GRID_);
  int gw = (int)gwf;
  int gh = (int)ghf;
  if (gy >= gh) return;       // wave-uniform

  float stepx = roi_w / gwf;
  float stepy = roi_h / ghf;

  float sy = y1 + ((float)gy + 0.5f) * stepy;
  bool iry = (sy > -1.0f) && (sy < (float)H_);
  float acc0 = 0.0f, acc1 = 0.0f;

  if (iry) {
    float cy = fmaxf(sy, 0.0f);
    int yl = (int)cy;
    yl = yl < (H_ - 1) ? yl : (H_ - 1);
    int yh = (yl + 1) < (H_ - 1) ? (yl + 1) : (H_ - 1);
    if (yl >= H_ - 1) cy = (float)yl;
    float fy = cy - (float)yl;
    float hy = 1.0f - fy;

    const unsigned short* zb = zf + (size_t)(roi >> 6) * (HW_ * C_);
    const unsigned short* rowl = zb + (size_t)yl * W_ * C_;
    const unsigned short* rowh = zb + (size_t)yh * W_ * C_;
    int co = c2 << 1;  // channel offset within a row (elements)

    for (int gx = 0; gx < gw; ++gx) {
      float sx = x1 + ((float)gx + 0.5f) * stepx;
      bool irx = (sx > -1.0f) && (sx < (float)W_);
      if (!irx) continue;
      float cx = fmaxf(sx, 0.0f);
      int xl = (int)cx;
      xl = xl < (W_ - 1) ? xl : (W_ - 1);
      int xh = (xl + 1) < (W_ - 1) ? (xl + 1) : (W_ - 1);
      if (xl >= W_ - 1) cx = (float)xl;
      float fx = cx - (float)xl;
      float hx = 1.0f - fx;

      float w11 = hy * hx, w12 = hy * fx, w21 = fy * hx, w22 = fy * fx;
      unsigned int v11 = *(const unsigned int*)(rowl + xl * C_ + co);
      unsigned int v12 = *(const unsigned int*)(rowl + xh * C_ + co);
      unsigned int v21 = *(const unsigned int*)(rowh + xl * C_ + co);
      unsigned int v22 = *(const unsigned int*)(rowh + xh * C_ + co);

      acc0 += w11 * __uint_as_float(v11 << 16)
            + w12 * __uint_as_float(v12 << 16)
            + w21 * __uint_as_float(v21 << 16)
            + w22 * __uint_as_float(v22 << 16);
      acc1 += w11 * __uint_as_float(v11 & 0xffff0000u)
            + w12 * __uint_as_float(v12 & 0xffff0000u)
            + w21 * __uint_as_float(v21 & 0xffff0000u)
            + w22 * __uint_as_float(v22 & 0xffff0000u);
    }
  }

  float2 res = make_float2(acc0, acc1);
  *(float2*)(partial + (size_t)(roi * MAX_GRID_ + gy) * C_ + (c2 << 1)) = res;
}

// ---------------------------------------------------------------------------
// Kernel 4: per-ROI reduce over gy rows, divide by gh*gw, then Linear with
// transposed weights (coalesced). One block (256 thr) per ROI.
// ---------------------------------------------------------------------------
__global__ __launch_bounds__(256) void final_kernel(
    const float* __restrict__ partial,  // [B*N, 16, C]
    const float* __restrict__ boxes,
    const float* __restrict__ Wt,       // [C, OUT_CH]
    const float* __restrict__ bias,
    float* __restrict__ out)            // [B*N, OUT_CH]
{
  int roi = blockIdx.x;
  int t   = threadIdx.x;
  int c   = t & 127;
  int h   = t >> 7;

  float4 bx = ((const float4*)boxes)[roi];
  float roi_w = (bx.z - bx.x) * SCALE_;
  float roi_h = (bx.w - bx.y) * SCALE_;
  float gwf = fminf(fmaxf(ceilf(roi_w), 1.0f), (float)MAX_GRID_);
  float ghf = fminf(fmaxf(ceilf(roi_h), 1.0f), (float)MAX_GRID_);
  int gh = (int)ghf;

  float s = 0.0f;
  for (int gy = h; gy < gh; gy += 2)
    s += partial[(size_t)(roi * MAX_GRID_ + gy) * C_ + c];

  __shared__ float tmp[256];
  __shared__ float feat[128];
  tmp[t] = s;
  __syncthreads();
  if (t < 128) feat[t] = (tmp[t] + tmp[t + 128]) * (1.0f / (ghf * gwf));
  __syncthreads();

  float sum = bias[t];
#pragma unroll
  for (int k = 0; k < C_; k += 4) {
    float4 f = *(const float4*)&feat[k];
    sum += f.x * Wt[(size_t)(k + 0) * OUT_CH_ + t]
         + f.y * Wt[(size_t)(k + 1) * OUT_CH_ + t]
         + f.z * Wt[(size_t)(k + 2) * OUT_CH_ + t]
         + f.w * Wt[(size_t)(k + 3) * OUT_CH_ + t];
  }
  out[(size_t)roi * OUT_CH_ + t] = sum;
}

extern "C" void kernel_launch(void* const* d_in, const int* in_sizes, int n_in,
                              void* d_out, int out_size, void* d_ws, size_t ws_size,
                              hipStream_t stream) {
  const float* z     = (const float*)d_in[0];  // [B,C,H,W]
  const float* boxes = (const float*)d_in[1];  // [B,N,4]
  const float* Wm    = (const float*)d_in[2];  // [OUT_CH,C]
  const float* bias  = (const float*)d_in[3];  // [OUT_CH]
  float* out = (float*)d_out;

  char* ws = (char*)d_ws;
  unsigned short* zf = (unsigned short*)ws;                       // 16.78 MB
  float* partial = (float*)(ws + (size_t)B_ * HW_ * C_ * 2);      // 8.39 MB
  float* Wt = (float*)(ws + (size_t)B_ * HW_ * C_ * 2
                          + (size_t)B_ * N_ * MAX_GRID_ * C_ * 4);// 128 KB

  transpose_bf16_kernel<<<dim3(HW_ / 128, B_), 256, 0, stream>>>(z, zf);
  wtrans_kernel<<<dim3(OUT_CH_ / 32, C_ / 32), dim3(32, 8), 0, stream>>>(Wm, Wt);
  gather_kernel<<<B_ * N_ * (MAX_GRID_ / 2), 128, 0, stream>>>(zf, boxes, partial);
  final_kernel<<<B_ * N_, 256, 0, stream>>>(partial, boxes, Wt, bias, out);
}